// Round 1
// baseline (235.070 us; speedup 1.0000x reference)
//
#include <hip/hip_runtime.h>

#define BB   8
#define LL   2048
#define DD   64
#define BM   32
#define BN   128
#define TPB  256
#define EPSF 1e-8f

// XOR-swizzled float4 pointer into a row-major [rows][64] f32 LDS tile.
// chunk index = row*16 + dg (dg = d/4), swizzled by XOR with (row>>2)&7 so
// b128 reads of 32 distinct rows spread across all 8 bank-groups.
__device__ __forceinline__ float4* swz(float* base, int row, int dg) {
    int ci = ((row << 4) + dg) ^ ((row >> 2) & 7);
    return reinterpret_cast<float4*>(base + (ci << 2));
}

__global__ __launch_bounds__(TPB) void att_cosine_kernel(
    const float* __restrict__ q, const float* __restrict__ y,
    float* __restrict__ out) {
    __shared__ float qs[BM * DD];   // 8 KB, normalized q rows (swizzled)
    __shared__ float ys[BN * DD];   // 32 KB, normalized y rows (swizzled)

    const int b       = blockIdx.y;
    const int rowBase = blockIdx.x * BM;
    const int t       = threadIdx.x;

    // ---- stage q tile, normalized (once per block) ----
    {
        const int row = t >> 3;   // 0..31
        const int oct = t & 7;    // 0..7  (8 lanes per row)
        const float* gq = q + ((size_t)b * LL + rowBase + row) * DD;
        float4 v0 = *reinterpret_cast<const float4*>(gq + oct * 4);
        float4 v1 = *reinterpret_cast<const float4*>(gq + 32 + oct * 4);
        float ss = v0.x*v0.x + v0.y*v0.y + v0.z*v0.z + v0.w*v0.w
                 + v1.x*v1.x + v1.y*v1.y + v1.z*v1.z + v1.w*v1.w;
        ss += __shfl_xor(ss, 1);
        ss += __shfl_xor(ss, 2);
        ss += __shfl_xor(ss, 4);
        const float sc = 1.0f / fmaxf(sqrtf(ss), EPSF);
        v0.x *= sc; v0.y *= sc; v0.z *= sc; v0.w *= sc;
        v1.x *= sc; v1.y *= sc; v1.z *= sc; v1.w *= sc;
        *swz(qs, row, oct)     = v0;
        *swz(qs, row, 8 + oct) = v1;
    }

    const int tx = t & 31;   // col group (32 -> 128 cols, 4 each)
    const int ty = t >> 5;   // row group (8  -> 32 rows, 4 each)
    float rmax[4] = {-1e30f, -1e30f, -1e30f, -1e30f};

    for (int ct = 0; ct < LL / BN; ++ct) {
        // ---- stage y tile, normalized ----
        {
            const int q4 = t & 3;   // 4 lanes per row
            const int r2 = t >> 2;  // 0..63
            #pragma unroll
            for (int p = 0; p < 2; ++p) {
                const int row = p * 64 + r2;  // 0..127
                const float* gy = y + ((size_t)b * LL + ct * BN + row) * DD;
                float4 v[4];
                #pragma unroll
                for (int l = 0; l < 4; ++l)
                    v[l] = *reinterpret_cast<const float4*>(gy + (l * 4 + q4) * 4);
                float ss = 0.0f;
                #pragma unroll
                for (int l = 0; l < 4; ++l)
                    ss += v[l].x*v[l].x + v[l].y*v[l].y + v[l].z*v[l].z + v[l].w*v[l].w;
                ss += __shfl_xor(ss, 1);
                ss += __shfl_xor(ss, 2);
                const float sc = 1.0f / fmaxf(sqrtf(ss), EPSF);
                #pragma unroll
                for (int l = 0; l < 4; ++l) {
                    v[l].x *= sc; v[l].y *= sc; v[l].z *= sc; v[l].w *= sc;
                    *swz(ys, row, l * 4 + q4) = v[l];
                }
            }
        }
        __syncthreads();

        // ---- 32x128 output tile, 4x4 per thread, K=64 in d-groups of 4 ----
        float acc[4][4] = {{0.f,0.f,0.f,0.f},{0.f,0.f,0.f,0.f},
                           {0.f,0.f,0.f,0.f},{0.f,0.f,0.f,0.f}};
        #pragma unroll 4
        for (int dg = 0; dg < 16; ++dg) {
            float4 qf[4], yf[4];
            #pragma unroll
            for (int i = 0; i < 4; ++i) qf[i] = *swz(qs, ty * 4 + i, dg);
            #pragma unroll
            for (int j = 0; j < 4; ++j) yf[j] = *swz(ys, tx * 4 + j, dg);
            #pragma unroll
            for (int i = 0; i < 4; ++i)
                #pragma unroll
                for (int j = 0; j < 4; ++j)
                    acc[i][j] += qf[i].x * yf[j].x + qf[i].y * yf[j].y
                               + qf[i].z * yf[j].z + qf[i].w * yf[j].w;
        }

        // ---- epilogue: coalesced float4 store + running row max ----
        float* po = out + (size_t)b * LL * LL + (size_t)rowBase * LL + ct * BN;
        #pragma unroll
        for (int i = 0; i < 4; ++i) {
            float4 v;
            v.x = acc[i][0]; v.y = acc[i][1]; v.z = acc[i][2]; v.w = acc[i][3];
            *reinterpret_cast<float4*>(po + (size_t)(ty * 4 + i) * LL + tx * 4) = v;
            rmax[i] = fmaxf(rmax[i],
                      fmaxf(fmaxf(acc[i][0], acc[i][1]), fmaxf(acc[i][2], acc[i][3])));
        }
        __syncthreads();  // protect ys before next stage
    }

    // ---- sim = max over cols: reduce across the 32 tx lanes ----
    #pragma unroll
    for (int i = 0; i < 4; ++i) {
        float v = rmax[i];
        v = fmaxf(v, __shfl_xor(v, 1));
        v = fmaxf(v, __shfl_xor(v, 2));
        v = fmaxf(v, __shfl_xor(v, 4));
        v = fmaxf(v, __shfl_xor(v, 8));
        v = fmaxf(v, __shfl_xor(v, 16));
        if (tx == 0)
            out[(size_t)BB * LL * LL + (size_t)b * LL + rowBase + ty * 4 + i] = v;
    }
}

extern "C" void kernel_launch(void* const* d_in, const int* in_sizes, int n_in,
                              void* d_out, int out_size, void* d_ws, size_t ws_size,
                              hipStream_t stream) {
    const float* q = (const float*)d_in[0];
    const float* y = (const float*)d_in[1];
    float* out     = (float*)d_out;
    dim3 grid(LL / BM, BB);  // 64 x 8 = 512 blocks -> 2 blocks/CU
    att_cosine_kernel<<<grid, dim3(TPB), 0, stream>>>(q, y, out);
}

// Round 2
// 161.625 us; speedup vs baseline: 1.4544x; 1.4544x over previous
//
#include <hip/hip_runtime.h>

#define LL 2048
#define DD 64
#define BB 8
#define EPSF 1e-8f

// ws layout (bf16 elements): [q_hi | y_hi | q_lo | y_lo], 2 MB each = 8 MB total.
#define NELEM ((size_t)BB * LL * DD)

typedef short bf16x8 __attribute__((ext_vector_type(8)));
typedef float f32x4 __attribute__((ext_vector_type(4)));

__device__ __forceinline__ ushort f2bf(float f) {  // RNE float->bf16
    uint u = __float_as_uint(f);
    return (ushort)((u + 0x7fffu + ((u >> 16) & 1u)) >> 16);
}
__device__ __forceinline__ float bf2f(ushort h) {
    return __uint_as_float((uint)h << 16);
}

// Normalize rows of q and y (fp32), split into bf16 hi + lo. 32 rows/block, 8 lanes/row.
__global__ __launch_bounds__(256) void norm_split_kernel(
    const float* __restrict__ q, const float* __restrict__ y,
    ushort* __restrict__ ws) {
    const int row   = blockIdx.x * 32 + (threadIdx.x >> 3);  // 0..16383
    const int oct   = threadIdx.x & 7;
    const int which = blockIdx.y;  // 0=q, 1=y
    const float* src = which ? y : q;
    ushort* hi = ws + (size_t)which * NELEM;
    ushort* lo = ws + 2 * NELEM + (size_t)which * NELEM;

    const float* g = src + (size_t)row * DD;
    float4 v0 = *reinterpret_cast<const float4*>(g + oct * 4);
    float4 v1 = *reinterpret_cast<const float4*>(g + 32 + oct * 4);
    float ss = v0.x*v0.x + v0.y*v0.y + v0.z*v0.z + v0.w*v0.w
             + v1.x*v1.x + v1.y*v1.y + v1.z*v1.z + v1.w*v1.w;
    ss += __shfl_xor(ss, 1);
    ss += __shfl_xor(ss, 2);
    ss += __shfl_xor(ss, 4);
    const float sc = 1.0f / fmaxf(sqrtf(ss), EPSF);

    const float f[8] = {v0.x*sc, v0.y*sc, v0.z*sc, v0.w*sc,
                        v1.x*sc, v1.y*sc, v1.z*sc, v1.w*sc};
    ushort h[8], l8[8];
    #pragma unroll
    for (int i = 0; i < 8; ++i) {
        h[i]  = f2bf(f[i]);
        l8[i] = f2bf(f[i] - bf2f(h[i]));
    }
    const size_t base = (size_t)row * DD + oct * 4;
    *reinterpret_cast<ushort4*>(hi + base)      = make_ushort4(h[0], h[1], h[2], h[3]);
    *reinterpret_cast<ushort4*>(hi + base + 32) = make_ushort4(h[4], h[5], h[6], h[7]);
    *reinterpret_cast<ushort4*>(lo + base)      = make_ushort4(l8[0], l8[1], l8[2], l8[3]);
    *reinterpret_cast<ushort4*>(lo + base + 32) = make_ushort4(l8[4], l8[5], l8[6], l8[7]);
}

// One block = (batch b, 32-row strip). 4 waves; wave w owns 64-col subtile of each
// 256-col step. MFMA 16x16x32 bf16, 3 products for fp32-level accuracy.
// A/B frag layout: lane&15 = row(A)/col(B), k = (lane>>4)*8 + j (8 contiguous bf16 = 16B).
__global__ __launch_bounds__(256) void att_mfma_kernel(
    const ushort* __restrict__ ws, float* __restrict__ out) {
    const int b       = blockIdx.y;
    const int rowBase = blockIdx.x * 32;
    const int t  = threadIdx.x;
    const int w  = t >> 6;
    const int l  = t & 63;
    const int ln = l & 15;
    const int kg = l >> 4;

    const ushort* qh = ws;
    const ushort* yh = ws + NELEM;
    const ushort* ql = ws + 2 * NELEM;
    const ushort* yl = ws + 3 * NELEM;

    // A fragments (q rows): loaded once, reused across all col tiles.
    bf16x8 ah[2][2], alo[2][2];
    #pragma unroll
    for (int m = 0; m < 2; ++m)
        #pragma unroll
        for (int kk = 0; kk < 2; ++kk) {
            const size_t off =
                ((size_t)(b * LL + rowBase + m * 16 + ln)) * DD + kk * 32 + kg * 8;
            ah[m][kk]  = *reinterpret_cast<const bf16x8*>(qh + off);
            alo[m][kk] = *reinterpret_cast<const bf16x8*>(ql + off);
        }

    float rmax[2][4];
    #pragma unroll
    for (int m = 0; m < 2; ++m)
        #pragma unroll
        for (int j = 0; j < 4; ++j) rmax[m][j] = -1e30f;

    for (int ct = 0; ct < 8; ++ct) {
        const int colBase = ct * 256 + w * 64;

        bf16x8 bh[4][2], bl[4][2];
        #pragma unroll
        for (int n = 0; n < 4; ++n)
            #pragma unroll
            for (int kk = 0; kk < 2; ++kk) {
                const size_t off =
                    ((size_t)(b * LL + colBase + n * 16 + ln)) * DD + kk * 32 + kg * 8;
                bh[n][kk] = *reinterpret_cast<const bf16x8*>(yh + off);
                bl[n][kk] = *reinterpret_cast<const bf16x8*>(yl + off);
            }

        f32x4 acc[2][4];
        #pragma unroll
        for (int m = 0; m < 2; ++m)
            #pragma unroll
            for (int n = 0; n < 4; ++n)
                acc[m][n] = (f32x4){0.f, 0.f, 0.f, 0.f};

        // lo*hi + hi*lo first, hi*hi last (all accumulate into same acc).
        #pragma unroll
        for (int kk = 0; kk < 2; ++kk)
            #pragma unroll
            for (int m = 0; m < 2; ++m)
                #pragma unroll
                for (int n = 0; n < 4; ++n)
                    acc[m][n] = __builtin_amdgcn_mfma_f32_16x16x32_bf16(
                        alo[m][kk], bh[n][kk], acc[m][n], 0, 0, 0);
        #pragma unroll
        for (int kk = 0; kk < 2; ++kk)
            #pragma unroll
            for (int m = 0; m < 2; ++m)
                #pragma unroll
                for (int n = 0; n < 4; ++n)
                    acc[m][n] = __builtin_amdgcn_mfma_f32_16x16x32_bf16(
                        ah[m][kk], bl[n][kk], acc[m][n], 0, 0, 0);
        #pragma unroll
        for (int kk = 0; kk < 2; ++kk)
            #pragma unroll
            for (int m = 0; m < 2; ++m)
                #pragma unroll
                for (int n = 0; n < 4; ++n)
                    acc[m][n] = __builtin_amdgcn_mfma_f32_16x16x32_bf16(
                        ah[m][kk], bh[n][kk], acc[m][n], 0, 0, 0);

        // C/D layout: col = lane&15, row = (lane>>4)*4 + j  [m89-verified].
        float* po = out + ((size_t)(b * LL + rowBase)) * LL + colBase;
        #pragma unroll
        for (int m = 0; m < 2; ++m)
            #pragma unroll
            for (int n = 0; n < 4; ++n)
                #pragma unroll
                for (int j = 0; j < 4; ++j) {
                    const float v = acc[m][n][j];
                    po[(size_t)(m * 16 + kg * 4 + j) * LL + n * 16 + ln] = v;
                    rmax[m][j] = fmaxf(rmax[m][j], v);
                }
    }

    // Column-max reduce: across the 16 lanes of each kg group (cols), then across waves.
    #pragma unroll
    for (int m = 0; m < 2; ++m)
        #pragma unroll
        for (int j = 0; j < 4; ++j) {
            float v = rmax[m][j];
            v = fmaxf(v, __shfl_xor(v, 1));
            v = fmaxf(v, __shfl_xor(v, 2));
            v = fmaxf(v, __shfl_xor(v, 4));
            v = fmaxf(v, __shfl_xor(v, 8));
            rmax[m][j] = v;
        }

    __shared__ float smax[4][32];
    if (ln == 0) {
        #pragma unroll
        for (int m = 0; m < 2; ++m)
            #pragma unroll
            for (int j = 0; j < 4; ++j)
                smax[w][m * 16 + kg * 4 + j] = rmax[m][j];
    }
    __syncthreads();
    if (t < 32) {
        const float v = fmaxf(fmaxf(smax[0][t], smax[1][t]),
                              fmaxf(smax[2][t], smax[3][t]));
        out[(size_t)BB * LL * LL + (size_t)b * LL + rowBase + t] = v;
    }
}

extern "C" void kernel_launch(void* const* d_in, const int* in_sizes, int n_in,
                              void* d_out, int out_size, void* d_ws, size_t ws_size,
                              hipStream_t stream) {
    const float* q = (const float*)d_in[0];
    const float* y = (const float*)d_in[1];
    float* out     = (float*)d_out;
    ushort* ws     = (ushort*)d_ws;  // needs 8 MB

    norm_split_kernel<<<dim3(512, 2), dim3(256), 0, stream>>>(q, y, ws);
    att_mfma_kernel<<<dim3(LL / 32, BB), dim3(256), 0, stream>>>(ws, out);
}